// Round 2
// baseline (400.577 us; speedup 1.0000x reference)
//
#include <hip/hip_runtime.h>
#include <hip/hip_bf16.h>
#include <math.h>

// Problem constants (from reference): N=100000 nodes, E=300000 edges, F=256.
#define FDIM 256

// ---------------------------------------------------------------------------
// CSR build: count -> scan (3 kernels) -> fill. Grouped by destination node.
// ---------------------------------------------------------------------------
__global__ void count_kernel(const int* __restrict__ dst, int* __restrict__ counts, int E) {
    int e = blockIdx.x * 256 + threadIdx.x;
    if (e < E) atomicAdd(&counts[dst[e]], 1);
}

__global__ void scan1_kernel(const int* __restrict__ counts, int* __restrict__ blksums, int N) {
    __shared__ int sd[256];
    int tid = threadIdx.x;
    int base = blockIdx.x * 1024 + tid * 4;
    int s = 0;
#pragma unroll
    for (int t = 0; t < 4; ++t) { int i = base + t; if (i < N) s += counts[i]; }
    sd[tid] = s; __syncthreads();
    for (int off = 128; off > 0; off >>= 1) {
        if (tid < off) sd[tid] += sd[tid + off];
        __syncthreads();
    }
    if (tid == 0) blksums[blockIdx.x] = sd[0];
}

// single block, 128 threads: exclusive-scan the (<=128) block sums
__global__ void scan2_kernel(int* __restrict__ blksums, int NB) {
    __shared__ int sd[128];
    int tid = threadIdx.x;
    int v = (tid < NB) ? blksums[tid] : 0;
    sd[tid] = v; __syncthreads();
    for (int off = 1; off < 128; off <<= 1) {
        int t = (tid >= off) ? sd[tid - off] : 0;
        __syncthreads();
        sd[tid] += t;
        __syncthreads();
    }
    if (tid < NB) blksums[tid] = sd[tid] - v;   // exclusive
}

__global__ void scan3_kernel(const int* __restrict__ counts, const int* __restrict__ blksums,
                             int* __restrict__ offsets, int* __restrict__ cursor,
                             float* __restrict__ dinv, int N, int E) {
    __shared__ int sd[256];
    int tid = threadIdx.x;
    int base = blockIdx.x * 1024 + tid * 4;
    int c[4]; int s = 0;
#pragma unroll
    for (int t = 0; t < 4; ++t) { int i = base + t; c[t] = (i < N) ? counts[i] : 0; s += c[t]; }
    sd[tid] = s; __syncthreads();
    int v = s;
    for (int off = 1; off < 256; off <<= 1) {
        int t = (tid >= off) ? sd[tid - off] : 0;
        __syncthreads();
        sd[tid] += t;
        __syncthreads();
    }
    int run = sd[tid] - v + blksums[blockIdx.x];  // exclusive prefix for this thread
#pragma unroll
    for (int t = 0; t < 4; ++t) {
        int i = base + t;
        if (i < N) {
            offsets[i] = run;
            cursor[i]  = run;
            // degree includes the self loop (+1); always > 0, matches reference
            dinv[i] = rsqrtf((float)(c[t] + 1));
            run += c[t];
        }
    }
    if (blockIdx.x == 0 && tid == 0) offsets[N] = E;
}

__global__ void fill_kernel(const int* __restrict__ src, const int* __restrict__ dst,
                            int* __restrict__ cursor, const float* __restrict__ dinv,
                            int* __restrict__ csr_src, float* __restrict__ csr_norm, int E) {
    int e = blockIdx.x * 256 + threadIdx.x;
    if (e < E) {
        int s = src[e], d = dst[e];
        int pos = atomicAdd(&cursor[d], 1);
        csr_src[pos]  = s;
        csr_norm[pos] = dinv[s] * dinv[d];
    }
}

// ---------------------------------------------------------------------------
// fp32 GEMM: H[N,256] = X[N,256] @ W[256,256]
// Tile: BM=64 rows x 256 cols, BK=32. 256 threads; each thread 8 rows x 8 cols.
// LDS per kk per lane: 64B for 128 FLOP (0.5 B/FLOP) -> LDS and VALU balanced.
// LDS: Xs 8.5KB + Ws 32KB = 41.5KB -> 3 blocks/CU (12 waves/CU).
// ---------------------------------------------------------------------------
__global__ __launch_bounds__(256) void gemm_kernel(const float* __restrict__ X,
                                                   const float* __restrict__ W,
                                                   float* __restrict__ H, int N) {
    __shared__ float Xs[32][68];    // [k][m], m=0..63; 68-pad keeps rows 16B-aligned (272B)
    __shared__ float Ws[32][256];   // [k][n]
    const int tid  = threadIdx.x;
    const int row0 = blockIdx.x * 64;
    const int r = tid >> 5;    // 0..7 -> rows 8r..8r+7
    const int c = tid & 31;    // cols 4c..4c+3 and 128+4c..128+4c+3

    float acc[8][8];
#pragma unroll
    for (int i = 0; i < 8; ++i)
#pragma unroll
        for (int j = 0; j < 8; ++j) acc[i][j] = 0.f;

    for (int k0 = 0; k0 < FDIM; k0 += 32) {
        // stage X tile transposed: thread owns row m=tid>>2, 8-wide K chunk kq=tid&3
        {
            const int m = tid >> 2, kq = tid & 3;
            const int row = row0 + m;
            float4 v0 = {0.f, 0.f, 0.f, 0.f}, v1 = {0.f, 0.f, 0.f, 0.f};
            if (row < N) {
                const float* s = X + (size_t)row * FDIM + k0 + 8 * kq;
                v0 = *(const float4*)s;
                v1 = *(const float4*)(s + 4);
            }
            Xs[8 * kq + 0][m] = v0.x; Xs[8 * kq + 1][m] = v0.y;
            Xs[8 * kq + 2][m] = v0.z; Xs[8 * kq + 3][m] = v0.w;
            Xs[8 * kq + 4][m] = v1.x; Xs[8 * kq + 5][m] = v1.y;
            Xs[8 * kq + 6][m] = v1.z; Xs[8 * kq + 7][m] = v1.w;
        }
        // stage W tile: k = j*4 + (tid>>6), n = (tid&63)*4 (contiguous 1KB per wave-row)
        {
            const int kk = tid >> 6;
            const int n  = (tid & 63) * 4;
#pragma unroll
            for (int j = 0; j < 8; ++j) {
                const int k = j * 4 + kk;
                *(float4*)(&Ws[k][n]) = *(const float4*)(W + (size_t)(k0 + k) * FDIM + n);
            }
        }
        __syncthreads();
#pragma unroll
        for (int kk = 0; kk < 32; ++kk) {
            float a[8], b[8];
            *(float4*)&a[0] = *(const float4*)(&Xs[kk][8 * r]);
            *(float4*)&a[4] = *(const float4*)(&Xs[kk][8 * r + 4]);
            *(float4*)&b[0] = *(const float4*)(&Ws[kk][4 * c]);
            *(float4*)&b[4] = *(const float4*)(&Ws[kk][128 + 4 * c]);
#pragma unroll
            for (int i = 0; i < 8; ++i)
#pragma unroll
                for (int j = 0; j < 8; ++j) acc[i][j] = fmaf(a[i], b[j], acc[i][j]);
        }
        __syncthreads();
    }
#pragma unroll
    for (int i = 0; i < 8; ++i) {
        const int row = row0 + 8 * r + i;
        if (row < N) {
            float* base = H + (size_t)row * FDIM;
            *(float4*)(base + 4 * c)       = *(float4*)&acc[i][0];
            *(float4*)(base + 128 + 4 * c) = *(float4*)&acc[i][4];
        }
    }
}

// ---------------------------------------------------------------------------
// Fused: per-node wave gathers neighbor rows of H, scaled accumulate,
// + self loop, + b_conv, ReLU, dot W_lin, + b_lin, sigmoid -> out[node]
// ---------------------------------------------------------------------------
__global__ __launch_bounds__(256) void agg_kernel(const float* __restrict__ h,
                                                  const int* __restrict__ offsets,
                                                  const int* __restrict__ csr_src,
                                                  const float* __restrict__ csr_norm,
                                                  const float* __restrict__ dinv,
                                                  const float* __restrict__ b_conv,
                                                  const float* __restrict__ W_lin,
                                                  const float* __restrict__ b_lin,
                                                  float* __restrict__ out, int N) {
    const int wid  = threadIdx.x >> 6;
    const int lane = threadIdx.x & 63;
    const int node = blockIdx.x * 4 + wid;
    if (node >= N) return;

    const float4* __restrict__ h4 = (const float4*)h;
    float4 acc = {0.f, 0.f, 0.f, 0.f};

    const int start = offsets[node];
    const int end   = offsets[node + 1];
    const float di  = dinv[node];

    for (int j = start; j < end; ++j) {
        const int s   = csr_src[j];
        const float w = csr_norm[j];
        const float4 v = h4[(size_t)s * 64 + lane];
        acc.x = fmaf(v.x, w, acc.x);
        acc.y = fmaf(v.y, w, acc.y);
        acc.z = fmaf(v.z, w, acc.z);
        acc.w = fmaf(v.w, w, acc.w);
    }
    {   // self loop
        const float w = di * di;
        const float4 v = h4[(size_t)node * 64 + lane];
        acc.x = fmaf(v.x, w, acc.x);
        acc.y = fmaf(v.y, w, acc.y);
        acc.z = fmaf(v.z, w, acc.z);
        acc.w = fmaf(v.w, w, acc.w);
    }
    const float4 bc = ((const float4*)b_conv)[lane];
    acc.x = fmaxf(acc.x + bc.x, 0.f);
    acc.y = fmaxf(acc.y + bc.y, 0.f);
    acc.z = fmaxf(acc.z + bc.z, 0.f);
    acc.w = fmaxf(acc.w + bc.w, 0.f);

    const float4 wl = ((const float4*)W_lin)[lane];
    float p = acc.x * wl.x + acc.y * wl.y + acc.z * wl.z + acc.w * wl.w;
#pragma unroll
    for (int off = 32; off > 0; off >>= 1) p += __shfl_xor(p, off);
    if (lane == 0) out[node] = 1.f / (1.f + expf(-(p + b_lin[0])));
}

// ---------------------------------------------------------------------------
extern "C" void kernel_launch(void* const* d_in, const int* in_sizes, int n_in,
                              void* d_out, int out_size, void* d_ws, size_t ws_size,
                              hipStream_t stream) {
    const float* x      = (const float*)d_in[0];
    const int*   eidx   = (const int*)d_in[1];
    const float* W_conv = (const float*)d_in[2];
    const float* b_conv = (const float*)d_in[3];
    const float* W_lin  = (const float*)d_in[4];
    const float* b_lin  = (const float*)d_in[5];
    float* out = (float*)d_out;

    const int N = in_sizes[0] / FDIM;      // 100000
    const int E = in_sizes[1] / 2;         // 300000
    const int* e_src = eidx;
    const int* e_dst = eidx + E;

    // workspace layout
    char* p = (char*)d_ws;
    float* h = (float*)p;           p += (size_t)N * FDIM * sizeof(float);
    int* counts   = (int*)p;        p += (size_t)N * sizeof(int);
    int* offsets  = (int*)p;        p += (size_t)(N + 1) * sizeof(int);
    int* cursor   = (int*)p;        p += (size_t)N * sizeof(int);
    float* dinv   = (float*)p;      p += (size_t)N * sizeof(float);
    int* csr_src  = (int*)p;        p += (size_t)E * sizeof(int);
    float* csr_norm = (float*)p;    p += (size_t)E * sizeof(float);
    int* blksums  = (int*)p;        p += 128 * sizeof(int);

    const int NB = (N + 1023) / 1024;   // 98 scan blocks

    hipMemsetAsync(counts, 0, (size_t)N * sizeof(int), stream);

    count_kernel<<<(E + 255) / 256, 256, 0, stream>>>(e_dst, counts, E);
    scan1_kernel<<<NB, 256, 0, stream>>>(counts, blksums, N);
    scan2_kernel<<<1, 128, 0, stream>>>(blksums, NB);
    scan3_kernel<<<NB, 256, 0, stream>>>(counts, blksums, offsets, cursor, dinv, N, E);
    fill_kernel<<<(E + 255) / 256, 256, 0, stream>>>(e_src, e_dst, cursor, dinv,
                                                     csr_src, csr_norm, E);

    gemm_kernel<<<(N + 63) / 64, 256, 0, stream>>>(x, W_conv, h, N);

    agg_kernel<<<(N + 3) / 4, 256, 0, stream>>>(h, offsets, csr_src, csr_norm, dinv,
                                                b_conv, W_lin, b_lin, out, N);
}

// Round 3
// 309.266 us; speedup vs baseline: 1.2953x; 1.2953x over previous
//
#include <hip/hip_runtime.h>
#include <hip/hip_bf16.h>
#include <math.h>

// Problem constants: N=100000 nodes, E=300000 edges, F=256.
#define FDIM 256

typedef short bfrag __attribute__((ext_vector_type(8)));   // 8 bf16 (4 VGPR)
typedef float f32x4 __attribute__((ext_vector_type(4)));

__device__ __forceinline__ short f2bf_rne(float f) {
    uint32_t u = __float_as_uint(f);
    uint32_t r = (u + 0x7FFFu + ((u >> 16) & 1u)) >> 16;
    return (short)r;
}
__device__ __forceinline__ float bf2f(short s) {
    return __uint_as_float(((uint32_t)(uint16_t)s) << 16);
}

#define GLOAD_LDS16(g, l) __builtin_amdgcn_global_load_lds(              \
    (const __attribute__((address_space(1))) void*)(g),                  \
    (__attribute__((address_space(3))) void*)(l), 16, 0, 0)

// ---------------------------------------------------------------------------
// CSR build: count -> scan (3 kernels) -> fill. Grouped by destination node.
// ---------------------------------------------------------------------------
__global__ void count_kernel(const int* __restrict__ dst, int* __restrict__ counts, int E) {
    int e = blockIdx.x * 256 + threadIdx.x;
    if (e < E) atomicAdd(&counts[dst[e]], 1);
}

__global__ void scan1_kernel(const int* __restrict__ counts, int* __restrict__ blksums, int N) {
    __shared__ int sd[256];
    int tid = threadIdx.x;
    int base = blockIdx.x * 1024 + tid * 4;
    int s = 0;
#pragma unroll
    for (int t = 0; t < 4; ++t) { int i = base + t; if (i < N) s += counts[i]; }
    sd[tid] = s; __syncthreads();
    for (int off = 128; off > 0; off >>= 1) {
        if (tid < off) sd[tid] += sd[tid + off];
        __syncthreads();
    }
    if (tid == 0) blksums[blockIdx.x] = sd[0];
}

__global__ void scan2_kernel(int* __restrict__ blksums, int NB) {
    __shared__ int sd[128];
    int tid = threadIdx.x;
    int v = (tid < NB) ? blksums[tid] : 0;
    sd[tid] = v; __syncthreads();
    for (int off = 1; off < 128; off <<= 1) {
        int t = (tid >= off) ? sd[tid - off] : 0;
        __syncthreads();
        sd[tid] += t;
        __syncthreads();
    }
    if (tid < NB) blksums[tid] = sd[tid] - v;   // exclusive
}

__global__ void scan3_kernel(const int* __restrict__ counts, const int* __restrict__ blksums,
                             int* __restrict__ offsets, int* __restrict__ cursor,
                             float* __restrict__ dinv, int N, int E) {
    __shared__ int sd[256];
    int tid = threadIdx.x;
    int base = blockIdx.x * 1024 + tid * 4;
    int c[4]; int s = 0;
#pragma unroll
    for (int t = 0; t < 4; ++t) { int i = base + t; c[t] = (i < N) ? counts[i] : 0; s += c[t]; }
    sd[tid] = s; __syncthreads();
    int v = s;
    for (int off = 1; off < 256; off <<= 1) {
        int t = (tid >= off) ? sd[tid - off] : 0;
        __syncthreads();
        sd[tid] += t;
        __syncthreads();
    }
    int run = sd[tid] - v + blksums[blockIdx.x];
#pragma unroll
    for (int t = 0; t < 4; ++t) {
        int i = base + t;
        if (i < N) {
            offsets[i] = run;
            cursor[i]  = run;
            dinv[i] = rsqrtf((float)(c[t] + 1));   // degree includes self loop
            run += c[t];
        }
    }
    if (blockIdx.x == 0 && tid == 0) offsets[N] = E;
}

__global__ void fill_kernel(const int* __restrict__ src, const int* __restrict__ dst,
                            int* __restrict__ cursor, const float* __restrict__ dinv,
                            int* __restrict__ csr_src, float* __restrict__ csr_norm, int E) {
    int e = blockIdx.x * 256 + threadIdx.x;
    if (e < E) {
        int s = src[e], d = dst[e];
        int pos = atomicAdd(&cursor[d], 1);
        csr_src[pos]  = s;
        csr_norm[pos] = dinv[s] * dinv[d];
    }
}

// ---------------------------------------------------------------------------
// W pre-split: W[k][n] fp32 -> Wt_hi/Wt_lo bf16 in GEMM-ready flat layout:
// idx = kstep*8192 + g*2048 + n*8 + j  where k = kstep*32 + g*8 + j.
// This equals the LDS layout [g][n][8], so global_load_lds stages it linearly.
// ---------------------------------------------------------------------------
__global__ void wsplit_kernel(const float* __restrict__ W,
                              short* __restrict__ Wh, short* __restrict__ Wl) {
    const int k = blockIdx.x;       // 0..255
    const int n = threadIdx.x;      // 0..255
    const float w = W[k * 256 + n];
    const short hi = f2bf_rne(w);
    const short lo = f2bf_rne(w - bf2f(hi));
    const int s = k >> 5, g = (k & 31) >> 3, j = k & 7;
    const size_t idx = (size_t)s * 8192 + g * 2048 + n * 8 + j;
    Wh[idx] = hi; Wl[idx] = lo;
}

// ---------------------------------------------------------------------------
// Split-bf16 MFMA GEMM: H[N,256] = X[N,256] @ W[256,256]
//   h = Xhi*Whi + Xhi*Wlo + Xlo*Whi  (3 MFMA products, fp32 accumulate)
// BM=128, BN=256 (full), BK=32; 512 threads = 8 waves (2 Mx4 N); each wave
// owns a 64x64 output = 4x4 frags of 16x16. kappa(g,j)=g*8+j used for BOTH
// A and B fragments -> correct for any hardware k-permutation.
// LDS [g][row][16B] subtiling -> frag ds_read_b128 are 2-way-conflict (free).
// ---------------------------------------------------------------------------
__global__ __launch_bounds__(512) void gemm_mfma(const float* __restrict__ X,
                                                 const short* __restrict__ Wth,
                                                 const short* __restrict__ Wtl,
                                                 float* __restrict__ H, int N) {
    __shared__ short Xh[4096], Xl[4096];   // [g][m 0..127][8]
    __shared__ short Wh[8192], Wl[8192];   // [g][n 0..255][8]

    const int tid  = threadIdx.x;
    const int lane = tid & 63;
    const int wid  = tid >> 6;          // 0..7
    const int wm   = wid >> 2;          // 0..1 -> rows wm*64
    const int wn   = wid & 3;           // 0..3 -> cols wn*64
    const int row0 = blockIdx.x * 128;

    // X staging map: thread owns row sm, k-chunk [8*sc .. 8*sc+7]
    const int sm = tid >> 2, sc = tid & 3;

    f32x4 acc[4][4];
#pragma unroll
    for (int i = 0; i < 4; ++i)
#pragma unroll
        for (int j = 0; j < 4; ++j) acc[i][j] = (f32x4){0.f, 0.f, 0.f, 0.f};

    float4 xv0, xv1;
    {   // load X regs for iter 0
        const int row = row0 + sm;
        if (row < N) {
            const float* s = X + (size_t)row * FDIM + 8 * sc;
            xv0 = *(const float4*)s; xv1 = *(const float4*)(s + 4);
        } else { xv0 = make_float4(0,0,0,0); xv1 = make_float4(0,0,0,0); }
    }

    const int g   = lane >> 4;
    const int r15 = lane & 15;

    for (int s = 0; s < 8; ++s) {
        // ---- stage X: convert fp32 regs -> hi/lo bf16, write [g=sc][m=sm][8]
        {
            const float v[8] = {xv0.x, xv0.y, xv0.z, xv0.w, xv1.x, xv1.y, xv1.z, xv1.w};
            bfrag hi8, lo8;
#pragma unroll
            for (int j = 0; j < 8; ++j) {
                const short h = f2bf_rne(v[j]);
                hi8[j] = h;
                lo8[j] = f2bf_rne(v[j] - bf2f(h));
            }
            *(bfrag*)(&Xh[(sc * 128 + sm) * 8]) = hi8;
            *(bfrag*)(&Xl[(sc * 128 + sm) * 8]) = lo8;
        }
        // ---- stage W: linear global_load_lds (layout matches LDS exactly)
        {
            const short* gh = Wth + s * 8192;
            const short* gl = Wtl + s * 8192;
            const int seg = wid * 512 + lane * 8;
#pragma unroll
            for (int p = 0; p < 2; ++p) {
                GLOAD_LDS16(gh + p * 4096 + seg, &Wh[p * 4096 + wid * 512]);
                GLOAD_LDS16(gl + p * 4096 + seg, &Wl[p * 4096 + wid * 512]);
            }
        }
        __syncthreads();   // staging visible (vmcnt+lgkm drained by barrier)

        // ---- prefetch X regs for next iter (hidden under MFMA)
        if (s < 7) {
            const int row = row0 + sm;
            if (row < N) {
                const float* src = X + (size_t)row * FDIM + (s + 1) * 32 + 8 * sc;
                xv0 = *(const float4*)src; xv1 = *(const float4*)(src + 4);
            } else { xv0 = make_float4(0,0,0,0); xv1 = make_float4(0,0,0,0); }
        }

        // ---- B fragments for this wave's 4 ni
        bfrag bh[4], bl[4];
#pragma unroll
        for (int ni = 0; ni < 4; ++ni) {
            const int off = (g * 256 + wn * 64 + ni * 16 + r15) * 8;
            bh[ni] = *(const bfrag*)(&Wh[off]);
            bl[ni] = *(const bfrag*)(&Wl[off]);
        }
        // ---- A fragments per mi, 3 MFMA per (mi,ni)
#pragma unroll
        for (int mi = 0; mi < 4; ++mi) {
            const int off = (g * 128 + wm * 64 + mi * 16 + r15) * 8;
            const bfrag ah = *(const bfrag*)(&Xh[off]);
            const bfrag al = *(const bfrag*)(&Xl[off]);
#pragma unroll
            for (int ni = 0; ni < 4; ++ni) {
                acc[mi][ni] = __builtin_amdgcn_mfma_f32_16x16x32_bf16(ah, bh[ni], acc[mi][ni], 0, 0, 0);
                acc[mi][ni] = __builtin_amdgcn_mfma_f32_16x16x32_bf16(ah, bl[ni], acc[mi][ni], 0, 0, 0);
                acc[mi][ni] = __builtin_amdgcn_mfma_f32_16x16x32_bf16(al, bh[ni], acc[mi][ni], 0, 0, 0);
            }
        }
        __syncthreads();   // LDS consumed; safe to restage
    }

    // ---- write C: D layout col=lane&15, row=(lane>>4)*4+reg  [m89 verified]
#pragma unroll
    for (int mi = 0; mi < 4; ++mi) {
        const int rowb = row0 + wm * 64 + mi * 16 + g * 4;
#pragma unroll
        for (int r = 0; r < 4; ++r) {
            const int row = rowb + r;
            if (row < N) {
                float* base = H + (size_t)row * FDIM + wn * 64 + r15;
#pragma unroll
                for (int ni = 0; ni < 4; ++ni) base[ni * 16] = acc[mi][ni][r];
            }
        }
    }
}

// ---------------------------------------------------------------------------
// Fused: per-node wave gathers neighbor rows of H, scaled accumulate,
// + self loop, + b_conv, ReLU, dot W_lin, + b_lin, sigmoid -> out[node]
// ---------------------------------------------------------------------------
__global__ __launch_bounds__(256) void agg_kernel(const float* __restrict__ h,
                                                  const int* __restrict__ offsets,
                                                  const int* __restrict__ csr_src,
                                                  const float* __restrict__ csr_norm,
                                                  const float* __restrict__ dinv,
                                                  const float* __restrict__ b_conv,
                                                  const float* __restrict__ W_lin,
                                                  const float* __restrict__ b_lin,
                                                  float* __restrict__ out, int N) {
    const int wid  = threadIdx.x >> 6;
    const int lane = threadIdx.x & 63;
    const int node = blockIdx.x * 4 + wid;
    if (node >= N) return;

    const float4* __restrict__ h4 = (const float4*)h;
    float4 acc = {0.f, 0.f, 0.f, 0.f};

    const int start = offsets[node];
    const int end   = offsets[node + 1];
    const float di  = dinv[node];

    for (int j = start; j < end; ++j) {
        const int s   = csr_src[j];
        const float w = csr_norm[j];
        const float4 v = h4[(size_t)s * 64 + lane];
        acc.x = fmaf(v.x, w, acc.x);
        acc.y = fmaf(v.y, w, acc.y);
        acc.z = fmaf(v.z, w, acc.z);
        acc.w = fmaf(v.w, w, acc.w);
    }
    {   // self loop
        const float w = di * di;
        const float4 v = h4[(size_t)node * 64 + lane];
        acc.x = fmaf(v.x, w, acc.x);
        acc.y = fmaf(v.y, w, acc.y);
        acc.z = fmaf(v.z, w, acc.z);
        acc.w = fmaf(v.w, w, acc.w);
    }
    const float4 bc = ((const float4*)b_conv)[lane];
    acc.x = fmaxf(acc.x + bc.x, 0.f);
    acc.y = fmaxf(acc.y + bc.y, 0.f);
    acc.z = fmaxf(acc.z + bc.z, 0.f);
    acc.w = fmaxf(acc.w + bc.w, 0.f);

    const float4 wl = ((const float4*)W_lin)[lane];
    float p = acc.x * wl.x + acc.y * wl.y + acc.z * wl.z + acc.w * wl.w;
#pragma unroll
    for (int off = 32; off > 0; off >>= 1) p += __shfl_xor(p, off);
    if (lane == 0) out[node] = 1.f / (1.f + expf(-(p + b_lin[0])));
}

// ---------------------------------------------------------------------------
extern "C" void kernel_launch(void* const* d_in, const int* in_sizes, int n_in,
                              void* d_out, int out_size, void* d_ws, size_t ws_size,
                              hipStream_t stream) {
    const float* x      = (const float*)d_in[0];
    const int*   eidx   = (const int*)d_in[1];
    const float* W_conv = (const float*)d_in[2];
    const float* b_conv = (const float*)d_in[3];
    const float* W_lin  = (const float*)d_in[4];
    const float* b_lin  = (const float*)d_in[5];
    float* out = (float*)d_out;

    const int N = in_sizes[0] / FDIM;      // 100000
    const int E = in_sizes[1] / 2;         // 300000
    const int* e_src = eidx;
    const int* e_dst = eidx + E;

    // workspace layout
    char* p = (char*)d_ws;
    float* h = (float*)p;           p += (size_t)N * FDIM * sizeof(float);
    int* counts   = (int*)p;        p += (size_t)N * sizeof(int);
    int* offsets  = (int*)p;        p += (size_t)(N + 1) * sizeof(int);
    int* cursor   = (int*)p;        p += (size_t)N * sizeof(int);
    float* dinv   = (float*)p;      p += (size_t)N * sizeof(float);
    int* csr_src  = (int*)p;        p += (size_t)E * sizeof(int);
    float* csr_norm = (float*)p;    p += (size_t)E * sizeof(float);
    int* blksums  = (int*)p;        p += 128 * sizeof(int);
    short* Wth    = (short*)p;      p += (size_t)FDIM * FDIM * sizeof(short);
    short* Wtl    = (short*)p;      p += (size_t)FDIM * FDIM * sizeof(short);

    const int NB = (N + 1023) / 1024;

    hipMemsetAsync(counts, 0, (size_t)N * sizeof(int), stream);

    count_kernel<<<(E + 255) / 256, 256, 0, stream>>>(e_dst, counts, E);
    scan1_kernel<<<NB, 256, 0, stream>>>(counts, blksums, N);
    scan2_kernel<<<1, 128, 0, stream>>>(blksums, NB);
    scan3_kernel<<<NB, 256, 0, stream>>>(counts, blksums, offsets, cursor, dinv, N, E);
    fill_kernel<<<(E + 255) / 256, 256, 0, stream>>>(e_src, e_dst, cursor, dinv,
                                                     csr_src, csr_norm, E);

    wsplit_kernel<<<FDIM, FDIM, 0, stream>>>(W_conv, Wth, Wtl);

    gemm_mfma<<<(N + 127) / 128, 512, 0, stream>>>(x, Wth, Wtl, h, N);

    agg_kernel<<<(N + 3) / 4, 256, 0, stream>>>(h, offsets, csr_src, csr_norm, dinv,
                                                b_conv, W_lin, b_lin, out, N);
}

// Round 5
// 286.813 us; speedup vs baseline: 1.3967x; 1.0783x over previous
//
#include <hip/hip_runtime.h>
#include <hip/hip_bf16.h>
#include <math.h>

// Problem constants: N=100000 nodes, E=300000 edges, F=256.
#define FDIM 256

typedef short bfrag __attribute__((ext_vector_type(8)));   // 8 bf16 (4 VGPR)
typedef float f32x4 __attribute__((ext_vector_type(4)));

__device__ __forceinline__ short f2bf_rne(float f) {
    uint32_t u = __float_as_uint(f);
    uint32_t r = (u + 0x7FFFu + ((u >> 16) & 1u)) >> 16;
    return (short)r;
}
__device__ __forceinline__ float bf2f(unsigned short s) {
    return __uint_as_float(((uint32_t)s) << 16);
}

#define GLOAD_LDS16(g, l) __builtin_amdgcn_global_load_lds(              \
    (const __attribute__((address_space(1))) void*)(g),                  \
    (__attribute__((address_space(3))) void*)(l), 16, 0, 0)

// ---------------------------------------------------------------------------
// CSR build: count -> scan (3 kernels) -> fill. Grouped by destination node.
// ---------------------------------------------------------------------------
__global__ void count_kernel(const int* __restrict__ dst, int* __restrict__ counts, int E) {
    int e = blockIdx.x * 256 + threadIdx.x;
    if (e < E) atomicAdd(&counts[dst[e]], 1);
}

__global__ void scan1_kernel(const int* __restrict__ counts, int* __restrict__ blksums, int N) {
    __shared__ int sd[256];
    int tid = threadIdx.x;
    int base = blockIdx.x * 1024 + tid * 4;
    int s = 0;
#pragma unroll
    for (int t = 0; t < 4; ++t) { int i = base + t; if (i < N) s += counts[i]; }
    sd[tid] = s; __syncthreads();
    for (int off = 128; off > 0; off >>= 1) {
        if (tid < off) sd[tid] += sd[tid + off];
        __syncthreads();
    }
    if (tid == 0) blksums[blockIdx.x] = sd[0];
}

__global__ void scan2_kernel(int* __restrict__ blksums, int NB) {
    __shared__ int sd[128];
    int tid = threadIdx.x;
    int v = (tid < NB) ? blksums[tid] : 0;
    sd[tid] = v; __syncthreads();
    for (int off = 1; off < 128; off <<= 1) {
        int t = (tid >= off) ? sd[tid - off] : 0;
        __syncthreads();
        sd[tid] += t;
        __syncthreads();
    }
    if (tid < NB) blksums[tid] = sd[tid] - v;   // exclusive
}

__global__ void scan3_kernel(const int* __restrict__ counts, const int* __restrict__ blksums,
                             int* __restrict__ offsets, int* __restrict__ cursor,
                             float* __restrict__ dinv, int N, int E) {
    __shared__ int sd[256];
    int tid = threadIdx.x;
    int base = blockIdx.x * 1024 + tid * 4;
    int c[4]; int s = 0;
#pragma unroll
    for (int t = 0; t < 4; ++t) { int i = base + t; c[t] = (i < N) ? counts[i] : 0; s += c[t]; }
    sd[tid] = s; __syncthreads();
    int v = s;
    for (int off = 1; off < 256; off <<= 1) {
        int t = (tid >= off) ? sd[tid - off] : 0;
        __syncthreads();
        sd[tid] += t;
        __syncthreads();
    }
    int run = sd[tid] - v + blksums[blockIdx.x];
#pragma unroll
    for (int t = 0; t < 4; ++t) {
        int i = base + t;
        if (i < N) {
            offsets[i] = run;
            cursor[i]  = run;
            dinv[i] = rsqrtf((float)(c[t] + 1));   // degree includes self loop
            run += c[t];
        }
    }
    if (blockIdx.x == 0 && tid == 0) offsets[N] = E;
}

__global__ void fill_kernel(const int* __restrict__ src, const int* __restrict__ dst,
                            int* __restrict__ cursor, const float* __restrict__ dinv,
                            int* __restrict__ csr_src, float* __restrict__ csr_norm, int E) {
    int e = blockIdx.x * 256 + threadIdx.x;
    if (e < E) {
        int s = src[e], d = dst[e];
        int pos = atomicAdd(&cursor[d], 1);
        csr_src[pos]  = s;
        csr_norm[pos] = dinv[s] * dinv[d];
    }
}

// ---------------------------------------------------------------------------
// W pre-split: W[k][n] fp32 -> hi/lo bf16, layout [s][n][g][8]:
//   idx = s*8192 + n*32 + g*8 + j   with k = s*32 + g*8 + j.
// Matches LDS layout [n][g][8] -> linear global_load_lds staging, and frag
// reads at [ (n*4+g)*8 ] are 64-lane-linear (conflict-free).
// ---------------------------------------------------------------------------
__global__ void wsplit_kernel(const float* __restrict__ W,
                              short* __restrict__ Wh, short* __restrict__ Wl) {
    const int k = blockIdx.x;       // 0..255
    const int n = threadIdx.x;      // 0..255
    const float w = W[k * 256 + n];
    const short hi = f2bf_rne(w);
    const short lo = f2bf_rne(w - bf2f((unsigned short)hi));
    const int s = k >> 5, g = (k & 31) >> 3, j = k & 7;
    const size_t idx = (size_t)s * 8192 + n * 32 + g * 8 + j;
    Wh[idx] = hi; Wl[idx] = lo;
}

// ---------------------------------------------------------------------------
// Split-bf16 MFMA GEMM, 2-phase double-buffered pipeline:
//   h = Xhi*Whi + Xhi*Wlo + Xlo*Whi   (fp32 accum; lo*lo dropped)
// BM=128, BN=256 (full), BK=32; 512 threads = 8 waves (2M x 4N), wave=64x64.
// Per iter: stage next tile (X reg->bf16 ds_write, W global_load_lds) FIRST,
// then ds_read+MFMA on current buffer, then ONE __syncthreads (its vmcnt(0)
// drain lands after the MFMA cluster -> staging latency hidden).
// LDS layout [row][g][8] -> all frag ds_read_b128 conflict-free.
// Output h stored as bf16 (halves write + downstream gather traffic).
// ---------------------------------------------------------------------------
__global__ __launch_bounds__(512) void gemm_mfma(const float* __restrict__ X,
                                                 const short* __restrict__ Wth,
                                                 const short* __restrict__ Wtl,
                                                 unsigned short* __restrict__ Hb, int N) {
    __shared__ short Xh[2][4096], Xl[2][4096];   // [buf][m 0..127][g 0..3][8]
    __shared__ short Wh[2][8192], Wl[2][8192];   // [buf][n 0..255][g 0..3][8]

    const int tid  = threadIdx.x;
    const int lane = tid & 63;
    const int wid  = tid >> 6;          // 0..7
    const int wm   = wid >> 2;          // 0..1 -> rows wm*64
    const int wn   = wid & 3;           // 0..3 -> cols wn*64
    const int row0 = blockIdx.x * 128;
    const int sm   = tid >> 2;          // staged X row 0..127
    const int g    = lane >> 4;
    const int r15  = lane & 15;

    f32x4 acc[4][4];
#pragma unroll
    for (int i = 0; i < 4; ++i)
#pragma unroll
        for (int j = 0; j < 4; ++j) acc[i][j] = (f32x4){0.f, 0.f, 0.f, 0.f};

    const int xrow = row0 + sm;
    const float* xbase = X + (size_t)xrow * FDIM + 8 * (tid & 3);

    float4 xa0, xa1;
    // ---- prologue: load+convert X for s=0, stage W for s=0
    if (xrow < N) { xa0 = *(const float4*)xbase; xa1 = *(const float4*)(xbase + 4); }
    else          { xa0 = make_float4(0,0,0,0); xa1 = make_float4(0,0,0,0); }
    {
        const float v[8] = {xa0.x,xa0.y,xa0.z,xa0.w,xa1.x,xa1.y,xa1.z,xa1.w};
        bfrag hi8, lo8;
#pragma unroll
        for (int j = 0; j < 8; ++j) {
            const short h = f2bf_rne(v[j]);
            hi8[j] = h; lo8[j] = f2bf_rne(v[j] - bf2f((unsigned short)h));
        }
        *(bfrag*)(&Xh[0][tid * 8]) = hi8;
        *(bfrag*)(&Xl[0][tid * 8]) = lo8;
    }
#pragma unroll
    for (int p = 0; p < 2; ++p) {
        GLOAD_LDS16(Wth + p * 4096 + wid * 512 + lane * 8, &Wh[0][p * 4096 + wid * 512]);
        GLOAD_LDS16(Wtl + p * 4096 + wid * 512 + lane * 8, &Wl[0][p * 4096 + wid * 512]);
    }
    // issue X regs for s=1
    if (xrow < N) { xa0 = *(const float4*)(xbase + 32); xa1 = *(const float4*)(xbase + 36); }
    else          { xa0 = make_float4(0,0,0,0); xa1 = make_float4(0,0,0,0); }
    __syncthreads();

    for (int s = 0; s < 8; ++s) {
        const int cur = s & 1, nxt = cur ^ 1;
        // ---- stage next tile (latency spans this iter's MFMA)
        if (s < 7) {
            const float v[8] = {xa0.x,xa0.y,xa0.z,xa0.w,xa1.x,xa1.y,xa1.z,xa1.w};
            bfrag hi8, lo8;
#pragma unroll
            for (int j = 0; j < 8; ++j) {
                const short h = f2bf_rne(v[j]);
                hi8[j] = h; lo8[j] = f2bf_rne(v[j] - bf2f((unsigned short)h));
            }
            *(bfrag*)(&Xh[nxt][tid * 8]) = hi8;
            *(bfrag*)(&Xl[nxt][tid * 8]) = lo8;
            const short* gh = Wth + (s + 1) * 8192;
            const short* gl = Wtl + (s + 1) * 8192;
#pragma unroll
            for (int p = 0; p < 2; ++p) {
                GLOAD_LDS16(gh + p * 4096 + wid * 512 + lane * 8, &Wh[nxt][p * 4096 + wid * 512]);
                GLOAD_LDS16(gl + p * 4096 + wid * 512 + lane * 8, &Wl[nxt][p * 4096 + wid * 512]);
            }
        }
        if (s < 6) {   // issue X regs for s+2
            if (xrow < N) {
                const float* src = xbase + (s + 2) * 32;
                xa0 = *(const float4*)src; xa1 = *(const float4*)(src + 4);
            } else { xa0 = make_float4(0,0,0,0); xa1 = make_float4(0,0,0,0); }
        }

        // ---- compute on current buffer
        bfrag bh[4], bl[4];
#pragma unroll
        for (int ni = 0; ni < 4; ++ni) {
            const int off = ((wn * 64 + ni * 16 + r15) * 4 + g) * 8;
            bh[ni] = *(const bfrag*)(&Wh[cur][off]);
            bl[ni] = *(const bfrag*)(&Wl[cur][off]);
        }
#pragma unroll
        for (int mi = 0; mi < 4; ++mi) {
            const int off = ((wm * 64 + mi * 16 + r15) * 4 + g) * 8;
            const bfrag ah = *(const bfrag*)(&Xh[cur][off]);
            const bfrag al = *(const bfrag*)(&Xl[cur][off]);
#pragma unroll
            for (int ni = 0; ni < 4; ++ni) {
                acc[mi][ni] = __builtin_amdgcn_mfma_f32_16x16x32_bf16(ah, bh[ni], acc[mi][ni], 0, 0, 0);
                acc[mi][ni] = __builtin_amdgcn_mfma_f32_16x16x32_bf16(ah, bl[ni], acc[mi][ni], 0, 0, 0);
                acc[mi][ni] = __builtin_amdgcn_mfma_f32_16x16x32_bf16(al, bh[ni], acc[mi][ni], 0, 0, 0);
            }
        }
        if (s < 7) __syncthreads();   // staging of nxt complete; safe to swap
    }

    // ---- epilogue: D layout col=lane&15, row=(lane>>4)*4+reg; store bf16
#pragma unroll
    for (int mi = 0; mi < 4; ++mi) {
        const int rowb = row0 + wm * 64 + mi * 16 + g * 4;
#pragma unroll
        for (int r = 0; r < 4; ++r) {
            const int row = rowb + r;
            if (row < N) {
                unsigned short* base = Hb + (size_t)row * FDIM + wn * 64 + r15;
#pragma unroll
                for (int ni = 0; ni < 4; ++ni)
                    base[ni * 16] = (unsigned short)f2bf_rne(acc[mi][ni][r]);
            }
        }
    }
}

// ---------------------------------------------------------------------------
// Fused: per-node wave gathers neighbor rows of bf16 H (8B/lane), scaled
// accumulate in fp32, + self loop, + b_conv, ReLU, dot W_lin, sigmoid.
// ---------------------------------------------------------------------------
__global__ __launch_bounds__(256) void agg_kernel(const unsigned short* __restrict__ hb,
                                                  const int* __restrict__ offsets,
                                                  const int* __restrict__ csr_src,
                                                  const float* __restrict__ csr_norm,
                                                  const float* __restrict__ dinv,
                                                  const float* __restrict__ b_conv,
                                                  const float* __restrict__ W_lin,
                                                  const float* __restrict__ b_lin,
                                                  float* __restrict__ out, int N) {
    const int wid  = threadIdx.x >> 6;
    const int lane = threadIdx.x & 63;
    const int node = blockIdx.x * 4 + wid;
    if (node >= N) return;

    float a0 = 0.f, a1 = 0.f, a2 = 0.f, a3 = 0.f;
    float c0 = 0.f, c1 = 0.f, c2 = 0.f, c3 = 0.f;

    const int start = offsets[node];
    const int end   = offsets[node + 1];
    const float di  = dinv[node];

    int j = start;
    for (; j + 1 < end; j += 2) {   // 2 independent chains for latency
        const int   s0 = csr_src[j],     s1 = csr_src[j + 1];
        const float w0 = csr_norm[j],    w1 = csr_norm[j + 1];
        const ushort4 v0 = *((const ushort4*)(hb + (size_t)s0 * FDIM) + lane);
        const ushort4 v1 = *((const ushort4*)(hb + (size_t)s1 * FDIM) + lane);
        a0 = fmaf(bf2f(v0.x), w0, a0); a1 = fmaf(bf2f(v0.y), w0, a1);
        a2 = fmaf(bf2f(v0.z), w0, a2); a3 = fmaf(bf2f(v0.w), w0, a3);
        c0 = fmaf(bf2f(v1.x), w1, c0); c1 = fmaf(bf2f(v1.y), w1, c1);
        c2 = fmaf(bf2f(v1.z), w1, c2); c3 = fmaf(bf2f(v1.w), w1, c3);
    }
    if (j < end) {
        const int   s0 = csr_src[j];
        const float w0 = csr_norm[j];
        const ushort4 v0 = *((const ushort4*)(hb + (size_t)s0 * FDIM) + lane);
        a0 = fmaf(bf2f(v0.x), w0, a0); a1 = fmaf(bf2f(v0.y), w0, a1);
        a2 = fmaf(bf2f(v0.z), w0, a2); a3 = fmaf(bf2f(v0.w), w0, a3);
    }
    {   // self loop
        const float w = di * di;
        const ushort4 v = *((const ushort4*)(hb + (size_t)node * FDIM) + lane);
        a0 = fmaf(bf2f(v.x), w, a0); a1 = fmaf(bf2f(v.y), w, a1);
        a2 = fmaf(bf2f(v.z), w, a2); a3 = fmaf(bf2f(v.w), w, a3);
    }
    a0 += c0; a1 += c1; a2 += c2; a3 += c3;

    const float4 bc = ((const float4*)b_conv)[lane];
    a0 = fmaxf(a0 + bc.x, 0.f); a1 = fmaxf(a1 + bc.y, 0.f);
    a2 = fmaxf(a2 + bc.z, 0.f); a3 = fmaxf(a3 + bc.w, 0.f);

    const float4 wl = ((const float4*)W_lin)[lane];
    float p = a0 * wl.x + a1 * wl.y + a2 * wl.z + a3 * wl.w;
#pragma unroll
    for (int off = 32; off > 0; off >>= 1) p += __shfl_xor(p, off);
    if (lane == 0) out[node] = 1.f / (1.f + expf(-(p + b_lin[0])));
}

// ---------------------------------------------------------------------------
extern "C" void kernel_launch(void* const* d_in, const int* in_sizes, int n_in,
                              void* d_out, int out_size, void* d_ws, size_t ws_size,
                              hipStream_t stream) {
    const float* x      = (const float*)d_in[0];
    const int*   eidx   = (const int*)d_in[1];
    const float* W_conv = (const float*)d_in[2];
    const float* b_conv = (const float*)d_in[3];
    const float* W_lin  = (const float*)d_in[4];
    const float* b_lin  = (const float*)d_in[5];
    float* out = (float*)d_out;

    const int N = in_sizes[0] / FDIM;      // 100000
    const int E = in_sizes[1] / 2;         // 300000
    const int* e_src = eidx;
    const int* e_dst = eidx + E;

    // workspace layout
    char* p = (char*)d_ws;
    unsigned short* hb = (unsigned short*)p; p += (size_t)N * FDIM * sizeof(unsigned short);
    int* counts   = (int*)p;        p += (size_t)N * sizeof(int);
    int* offsets  = (int*)p;        p += (size_t)(N + 1) * sizeof(int);
    int* cursor   = (int*)p;        p += (size_t)N * sizeof(int);
    float* dinv   = (float*)p;      p += (size_t)N * sizeof(float);
    int* csr_src  = (int*)p;        p += (size_t)E * sizeof(int);
    float* csr_norm = (float*)p;    p += (size_t)E * sizeof(float);
    int* blksums  = (int*)p;        p += 128 * sizeof(int);
    short* Wth    = (short*)p;      p += (size_t)FDIM * FDIM * sizeof(short);
    short* Wtl    = (short*)p;      p += (size_t)FDIM * FDIM * sizeof(short);

    const int NB = (N + 1023) / 1024;

    hipMemsetAsync(counts, 0, (size_t)N * sizeof(int), stream);

    count_kernel<<<(E + 255) / 256, 256, 0, stream>>>(e_dst, counts, E);
    scan1_kernel<<<NB, 256, 0, stream>>>(counts, blksums, N);
    scan2_kernel<<<1, 128, 0, stream>>>(blksums, NB);
    scan3_kernel<<<NB, 256, 0, stream>>>(counts, blksums, offsets, cursor, dinv, N, E);
    fill_kernel<<<(E + 255) / 256, 256, 0, stream>>>(e_src, e_dst, cursor, dinv,
                                                     csr_src, csr_norm, E);

    wsplit_kernel<<<FDIM, FDIM, 0, stream>>>(W_conv, Wth, Wtl);

    gemm_mfma<<<(N + 127) / 128, 512, 0, stream>>>(x, Wth, Wtl, hb, N);

    agg_kernel<<<(N + 3) / 4, 256, 0, stream>>>(hb, offsets, csr_src, csr_norm, dinv,
                                                b_conv, W_lin, b_lin, out, N);
}

// Round 6
// 269.190 us; speedup vs baseline: 1.4881x; 1.0655x over previous
//
#include <hip/hip_runtime.h>
#include <hip/hip_bf16.h>
#include <math.h>

// Problem constants: N=100000 nodes, E=300000 edges, F=256.
#define FDIM 256

typedef short bfrag __attribute__((ext_vector_type(8)));   // 8 bf16 (4 VGPR)
typedef short s16x4 __attribute__((ext_vector_type(4)));
typedef float f32x4 __attribute__((ext_vector_type(4)));
typedef unsigned short u16x8 __attribute__((ext_vector_type(8)));

__device__ __forceinline__ short f2bf_rne(float f) {
    uint32_t u = __float_as_uint(f);
    uint32_t r = (u + 0x7FFFu + ((u >> 16) & 1u)) >> 16;
    return (short)r;
}
__device__ __forceinline__ float bf2f(unsigned short s) {
    return __uint_as_float(((uint32_t)s) << 16);
}

#define GLOAD_LDS16(g, l) __builtin_amdgcn_global_load_lds(              \
    (const __attribute__((address_space(1))) void*)(g),                  \
    (__attribute__((address_space(3))) void*)(l), 16, 0, 0)

// ---------------------------------------------------------------------------
// CSR build: count -> scan (3 kernels) -> fill. Grouped by destination node.
// ---------------------------------------------------------------------------
__global__ void count_kernel(const int* __restrict__ dst, int* __restrict__ counts, int E) {
    int e = blockIdx.x * 256 + threadIdx.x;
    if (e < E) atomicAdd(&counts[dst[e]], 1);
}

__global__ void scan1_kernel(const int* __restrict__ counts, int* __restrict__ blksums, int N) {
    __shared__ int sd[256];
    int tid = threadIdx.x;
    int base = blockIdx.x * 1024 + tid * 4;
    int s = 0;
#pragma unroll
    for (int t = 0; t < 4; ++t) { int i = base + t; if (i < N) s += counts[i]; }
    sd[tid] = s; __syncthreads();
    for (int off = 128; off > 0; off >>= 1) {
        if (tid < off) sd[tid] += sd[tid + off];
        __syncthreads();
    }
    if (tid == 0) blksums[blockIdx.x] = sd[0];
}

__global__ void scan2_kernel(int* __restrict__ blksums, int NB) {
    __shared__ int sd[128];
    int tid = threadIdx.x;
    int v = (tid < NB) ? blksums[tid] : 0;
    sd[tid] = v; __syncthreads();
    for (int off = 1; off < 128; off <<= 1) {
        int t = (tid >= off) ? sd[tid - off] : 0;
        __syncthreads();
        sd[tid] += t;
        __syncthreads();
    }
    if (tid < NB) blksums[tid] = sd[tid] - v;   // exclusive
}

__global__ void scan3_kernel(const int* __restrict__ counts, const int* __restrict__ blksums,
                             int* __restrict__ offsets, int* __restrict__ cursor,
                             float* __restrict__ dinv, int N, int E) {
    __shared__ int sd[256];
    int tid = threadIdx.x;
    int base = blockIdx.x * 1024 + tid * 4;
    int c[4]; int s = 0;
#pragma unroll
    for (int t = 0; t < 4; ++t) { int i = base + t; c[t] = (i < N) ? counts[i] : 0; s += c[t]; }
    sd[tid] = s; __syncthreads();
    int v = s;
    for (int off = 1; off < 256; off <<= 1) {
        int t = (tid >= off) ? sd[tid - off] : 0;
        __syncthreads();
        sd[tid] += t;
        __syncthreads();
    }
    int run = sd[tid] - v + blksums[blockIdx.x];
#pragma unroll
    for (int t = 0; t < 4; ++t) {
        int i = base + t;
        if (i < N) {
            offsets[i] = run;
            cursor[i]  = run;
            dinv[i] = rsqrtf((float)(c[t] + 1));   // degree includes self loop
            run += c[t];
        }
    }
    if (blockIdx.x == 0 && tid == 0) offsets[N] = E;
}

__global__ void fill_kernel(const int* __restrict__ src, const int* __restrict__ dst,
                            int* __restrict__ cursor, int* __restrict__ csr_src, int E) {
    int e = blockIdx.x * 256 + threadIdx.x;
    if (e < E) {
        int s = src[e], d = dst[e];
        int pos = atomicAdd(&cursor[d], 1);
        csr_src[pos] = s;
    }
}

// ---------------------------------------------------------------------------
// W pre-split: W[k][n] fp32 -> hi/lo bf16, layout [s][n][g][8]:
//   idx = s*8192 + n*32 + g*8 + j   with k = s*32 + g*8 + j.
// Matches LDS layout [n][g][8] -> linear global_load_lds staging; frag reads
// are 64-lane permutations of contiguous 1KB (conflict-free).
// ---------------------------------------------------------------------------
__global__ void wsplit_kernel(const float* __restrict__ W,
                              short* __restrict__ Wh, short* __restrict__ Wl) {
    const int k = blockIdx.x;       // 0..255
    const int n = threadIdx.x;      // 0..255
    const float w = W[k * 256 + n];
    const short hi = f2bf_rne(w);
    const short lo = f2bf_rne(w - bf2f((unsigned short)hi));
    const int s = k >> 5, g = (k & 31) >> 3, j = k & 7;
    const size_t idx = (size_t)s * 8192 + n * 32 + g * 8 + j;
    Wh[idx] = hi; Wl[idx] = lo;
}

// ---------------------------------------------------------------------------
// Split-bf16 MFMA GEMM, 2-phase double-buffered, 2 blocks/CU:
//   h = (Xhi*Whi + Xhi*Wlo + Xlo*Whi) * dinv[row]  -> bf16
// BM=64, BN=256, BK=32; 512 threads = 8 waves (2M x 4N), wave tile 32x64.
// LDS 80KB (X 16K + W 64K, both dbuf) -> 2 blocks/CU, 4 waves/SIMD.
// MFMA product-major: 8 independent MFMAs between accumulator reuses.
// Single barrier per iter; staging issued before MFMA cluster.
// ---------------------------------------------------------------------------
__global__ __launch_bounds__(512, 4) void gemm_mfma(const float* __restrict__ X,
                                                    const short* __restrict__ Wth,
                                                    const short* __restrict__ Wtl,
                                                    const float* __restrict__ dinv,
                                                    unsigned short* __restrict__ Hb, int N) {
    __shared__ short Xh[2][2048], Xl[2][2048];   // [buf][row 0..63][g][8]
    __shared__ short Wh[2][8192], Wl[2][8192];   // [buf][n 0..255][g][8]

    const int tid  = threadIdx.x;
    const int lane = tid & 63;
    const int wid  = tid >> 6;          // 0..7
    const int wm   = wid >> 2;          // 0..1 -> rows wm*32
    const int wn   = wid & 3;           // 0..3 -> cols wn*64
    const int row0 = blockIdx.x * 64;
    const int g    = lane >> 4;
    const int r15  = lane & 15;

    // X staging map: thread owns row srow, 4-float chunk skq
    const int srow = tid >> 3, skq = tid & 7;
    const int sg = skq >> 1, sj = (skq & 1) * 4;
    const int xoff = (srow * 4 + sg) * 8 + sj;
    const int xrow = row0 + srow;
    const float* xptr = X + (size_t)xrow * FDIM + skq * 4;

    f32x4 acc[2][4];
#pragma unroll
    for (int i = 0; i < 2; ++i)
#pragma unroll
        for (int j = 0; j < 4; ++j) acc[i][j] = (f32x4){0.f, 0.f, 0.f, 0.f};

    float4 xa;
    // ---- prologue: stage s=0
    xa = (xrow < N) ? *(const float4*)xptr : make_float4(0, 0, 0, 0);
    {
        const float v[4] = {xa.x, xa.y, xa.z, xa.w};
        s16x4 hi4, lo4;
#pragma unroll
        for (int j = 0; j < 4; ++j) {
            const short h = f2bf_rne(v[j]);
            hi4[j] = h; lo4[j] = f2bf_rne(v[j] - bf2f((unsigned short)h));
        }
        *(s16x4*)(&Xh[0][xoff]) = hi4;
        *(s16x4*)(&Xl[0][xoff]) = lo4;
    }
#pragma unroll
    for (int p = 0; p < 2; ++p) {
        GLOAD_LDS16(Wth + p * 4096 + tid * 8, &Wh[0][p * 4096 + tid * 8]);
        GLOAD_LDS16(Wtl + p * 4096 + tid * 8, &Wl[0][p * 4096 + tid * 8]);
    }
    xa = (xrow < N) ? *(const float4*)(xptr + 32) : make_float4(0, 0, 0, 0);
    __syncthreads();

    for (int s = 0; s < 8; ++s) {
        const int cur = s & 1, nxt = cur ^ 1;
        // ---- stage next tile (latency spans this iter's MFMA cluster)
        if (s < 7) {
            const float v[4] = {xa.x, xa.y, xa.z, xa.w};
            s16x4 hi4, lo4;
#pragma unroll
            for (int j = 0; j < 4; ++j) {
                const short h = f2bf_rne(v[j]);
                hi4[j] = h; lo4[j] = f2bf_rne(v[j] - bf2f((unsigned short)h));
            }
            *(s16x4*)(&Xh[nxt][xoff]) = hi4;
            *(s16x4*)(&Xl[nxt][xoff]) = lo4;
            const short* gh = Wth + (s + 1) * 8192;
            const short* gl = Wtl + (s + 1) * 8192;
#pragma unroll
            for (int p = 0; p < 2; ++p) {
                GLOAD_LDS16(gh + p * 4096 + tid * 8, &Wh[nxt][p * 4096 + tid * 8]);
                GLOAD_LDS16(gl + p * 4096 + tid * 8, &Wl[nxt][p * 4096 + tid * 8]);
            }
        }
        if (s < 6)
            xa = (xrow < N) ? *(const float4*)(xptr + (s + 2) * 32) : make_float4(0, 0, 0, 0);

        // ---- load all fragments, then product-major MFMA (dep distance 8)
        bfrag ah[2], al[2], bh[4], bl[4];
#pragma unroll
        for (int mi = 0; mi < 2; ++mi) {
            const int off = ((wm * 32 + mi * 16 + r15) * 4 + g) * 8;
            ah[mi] = *(const bfrag*)(&Xh[cur][off]);
            al[mi] = *(const bfrag*)(&Xl[cur][off]);
        }
#pragma unroll
        for (int ni = 0; ni < 4; ++ni) {
            const int off = ((wn * 64 + ni * 16 + r15) * 4 + g) * 8;
            bh[ni] = *(const bfrag*)(&Wh[cur][off]);
            bl[ni] = *(const bfrag*)(&Wl[cur][off]);
        }
#pragma unroll
        for (int mi = 0; mi < 2; ++mi)
#pragma unroll
            for (int ni = 0; ni < 4; ++ni)
                acc[mi][ni] = __builtin_amdgcn_mfma_f32_16x16x32_bf16(ah[mi], bh[ni], acc[mi][ni], 0, 0, 0);
#pragma unroll
        for (int mi = 0; mi < 2; ++mi)
#pragma unroll
            for (int ni = 0; ni < 4; ++ni)
                acc[mi][ni] = __builtin_amdgcn_mfma_f32_16x16x32_bf16(ah[mi], bl[ni], acc[mi][ni], 0, 0, 0);
#pragma unroll
        for (int mi = 0; mi < 2; ++mi)
#pragma unroll
            for (int ni = 0; ni < 4; ++ni)
                acc[mi][ni] = __builtin_amdgcn_mfma_f32_16x16x32_bf16(al[mi], bh[ni], acc[mi][ni], 0, 0, 0);

        if (s < 7) __syncthreads();
    }

    // ---- epilogue: D layout col=lane&15, row=(lane>>4)*4+reg; store bf16*dinv
#pragma unroll
    for (int mi = 0; mi < 2; ++mi) {
        const int rowb = row0 + wm * 32 + mi * 16 + g * 4;
#pragma unroll
        for (int r = 0; r < 4; ++r) {
            const int row = rowb + r;
            if (row < N) {
                const float dv = dinv[row];
                unsigned short* base = Hb + (size_t)row * FDIM + wn * 64 + r15;
#pragma unroll
                for (int ni = 0; ni < 4; ++ni)
                    base[ni * 16] = (unsigned short)f2bf_rne(acc[mi][ni][r] * dv);
            }
        }
    }
}

// ---------------------------------------------------------------------------
// Fused aggregation: one 16-lane group per node (16 nodes/block).
// hb rows are pre-scaled by dinv[src]; result = dinv[dst]*sum + b_conv,
// then ReLU, dot W_lin, + b_lin, sigmoid -> out[node].
// 32 B/lane gathers; 128 nodes in flight per CU (4x prev latency hiding).
// ---------------------------------------------------------------------------
__global__ __launch_bounds__(256) void agg_kernel(const unsigned short* __restrict__ hb,
                                                  const int* __restrict__ offsets,
                                                  const int* __restrict__ csr_src,
                                                  const float* __restrict__ dinv,
                                                  const float* __restrict__ b_conv,
                                                  const float* __restrict__ W_lin,
                                                  const float* __restrict__ b_lin,
                                                  float* __restrict__ out, int N) {
    const int t    = threadIdx.x;
    const int l16  = t & 15;
    const int node = blockIdx.x * 16 + (t >> 4);
    if (node >= N) return;

    const int start = offsets[node];
    const int end   = offsets[node + 1];

    float acc[16];
    {   // self loop row (issued first)
        const unsigned short* r = hb + (size_t)node * FDIM + l16 * 16;
        const u16x8 u0 = *(const u16x8*)r, u1 = *(const u16x8*)(r + 8);
#pragma unroll
        for (int k = 0; k < 8; ++k) { acc[k] = bf2f(u0[k]); acc[8 + k] = bf2f(u1[k]); }
    }
    for (int j = start; j < end; ++j) {
        const unsigned short* r = hb + (size_t)csr_src[j] * FDIM + l16 * 16;
        const u16x8 u0 = *(const u16x8*)r, u1 = *(const u16x8*)(r + 8);
#pragma unroll
        for (int k = 0; k < 8; ++k) { acc[k] += bf2f(u0[k]); acc[8 + k] += bf2f(u1[k]); }
    }

    const float dv = dinv[node];
    float p = 0.f;
#pragma unroll
    for (int q = 0; q < 4; ++q) {
        const float4 bc = *(const float4*)(b_conv + l16 * 16 + q * 4);
        const float4 wl = *(const float4*)(W_lin  + l16 * 16 + q * 4);
        p = fmaf(fmaxf(fmaf(acc[q * 4 + 0], dv, bc.x), 0.f), wl.x, p);
        p = fmaf(fmaxf(fmaf(acc[q * 4 + 1], dv, bc.y), 0.f), wl.y, p);
        p = fmaf(fmaxf(fmaf(acc[q * 4 + 2], dv, bc.z), 0.f), wl.z, p);
        p = fmaf(fmaxf(fmaf(acc[q * 4 + 3], dv, bc.w), 0.f), wl.w, p);
    }
#pragma unroll
    for (int off = 1; off < 16; off <<= 1) p += __shfl_xor(p, off);
    if (l16 == 0) out[node] = 1.f / (1.f + expf(-(p + b_lin[0])));
}

// ---------------------------------------------------------------------------
extern "C" void kernel_launch(void* const* d_in, const int* in_sizes, int n_in,
                              void* d_out, int out_size, void* d_ws, size_t ws_size,
                              hipStream_t stream) {
    const float* x      = (const float*)d_in[0];
    const int*   eidx   = (const int*)d_in[1];
    const float* W_conv = (const float*)d_in[2];
    const float* b_conv = (const float*)d_in[3];
    const float* W_lin  = (const float*)d_in[4];
    const float* b_lin  = (const float*)d_in[5];
    float* out = (float*)d_out;

    const int N = in_sizes[0] / FDIM;      // 100000
    const int E = in_sizes[1] / 2;         // 300000
    const int* e_src = eidx;
    const int* e_dst = eidx + E;

    // workspace layout
    char* p = (char*)d_ws;
    unsigned short* hb = (unsigned short*)p; p += (size_t)N * FDIM * sizeof(unsigned short);
    int* counts   = (int*)p;        p += (size_t)N * sizeof(int);
    int* offsets  = (int*)p;        p += (size_t)(N + 1) * sizeof(int);
    int* cursor   = (int*)p;        p += (size_t)N * sizeof(int);
    float* dinv   = (float*)p;      p += (size_t)N * sizeof(float);
    int* csr_src  = (int*)p;        p += (size_t)E * sizeof(int);
    int* blksums  = (int*)p;        p += 128 * sizeof(int);
    short* Wth    = (short*)p;      p += (size_t)FDIM * FDIM * sizeof(short);
    short* Wtl    = (short*)p;      p += (size_t)FDIM * FDIM * sizeof(short);

    const int NB = (N + 1023) / 1024;

    hipMemsetAsync(counts, 0, (size_t)N * sizeof(int), stream);

    count_kernel<<<(E + 255) / 256, 256, 0, stream>>>(e_dst, counts, E);
    scan1_kernel<<<NB, 256, 0, stream>>>(counts, blksums, N);
    scan2_kernel<<<1, 128, 0, stream>>>(blksums, NB);
    scan3_kernel<<<NB, 256, 0, stream>>>(counts, blksums, offsets, cursor, dinv, N, E);
    fill_kernel<<<(E + 255) / 256, 256, 0, stream>>>(e_src, e_dst, cursor, csr_src, E);

    wsplit_kernel<<<FDIM, FDIM, 0, stream>>>(W_conv, Wth, Wtl);

    gemm_mfma<<<(N + 63) / 64, 512, 0, stream>>>(x, Wth, Wtl, dinv, hb, N);

    agg_kernel<<<(N + 15) / 16, 256, 0, stream>>>(hb, offsets, csr_src, dinv,
                                                  b_conv, W_lin, b_lin, out, N);
}